// Round 1
// baseline (8191.501 us; speedup 1.0000x reference)
//
#include <hip/hip_runtime.h>

#define DFEAT 64

// ---------------------------------------------------------------------------
// init: X_out = max(outdeg,1e-8)*H ; X_in = max(indeg,1e-8)*H ; zero hop-0
// destination buffers; thread 0 computes softmax(hop_att)*theta coefs.
// ---------------------------------------------------------------------------
__global__ void init_kernel(const float* __restrict__ H,
                            const float* __restrict__ outdeg,
                            const float* __restrict__ indeg,
                            const float* __restrict__ hop_att,
                            const float* __restrict__ th_out,
                            const float* __restrict__ th_in,
                            float* __restrict__ XAout, float* __restrict__ XAin,
                            float* __restrict__ XBout, float* __restrict__ XBin,
                            float* __restrict__ coefs,
                            int n4) {
    int idx = blockIdx.x * blockDim.x + threadIdx.x;
    if (idx == 0) {
        float m = fmaxf(fmaxf(hop_att[0], hop_att[1]), hop_att[2]);
        float e0 = __expf(hop_att[0] - m);
        float e1 = __expf(hop_att[1] - m);
        float e2 = __expf(hop_att[2] - m);
        float inv = 1.0f / (e0 + e1 + e2);
        coefs[0] = e0 * inv * th_out[0]; coefs[1] = e0 * inv * th_in[0];
        coefs[2] = e1 * inv * th_out[1]; coefs[3] = e1 * inv * th_in[1];
        coefs[4] = e2 * inv * th_out[2]; coefs[5] = e2 * inv * th_in[2];
    }
    if (idx >= n4) return;
    int row = idx >> 4;                       // 16 float4 per 64-wide row
    float4 h = reinterpret_cast<const float4*>(H)[idx];
    float doo = fmaxf(outdeg[row], 1e-8f);
    float dii = fmaxf(indeg[row], 1e-8f);
    float4 xo = make_float4(h.x * doo, h.y * doo, h.z * doo, h.w * doo);
    float4 xi = make_float4(h.x * dii, h.y * dii, h.z * dii, h.w * dii);
    float4 z = make_float4(0.f, 0.f, 0.f, 0.f);
    reinterpret_cast<float4*>(XAout)[idx] = xo;
    reinterpret_cast<float4*>(XAin)[idx]  = xi;
    reinterpret_cast<float4*>(XBout)[idx] = z;
    reinterpret_cast<float4*>(XBin)[idx]  = z;
}

// ---------------------------------------------------------------------------
// spmm (both directions in one launch): 16 threads per edge, float4 per thread.
// dir 0: Yout[row] += val * Xout[col]      (A  @ X)
// dir 1: Yin [col] += val * Xin [row]      (A^T @ X)
// ---------------------------------------------------------------------------
__global__ void spmm_kernel(const int* __restrict__ erow,
                            const int* __restrict__ ecol,
                            const float* __restrict__ eval,
                            const float* __restrict__ Xout, float* __restrict__ Yout,
                            const float* __restrict__ Xin,  float* __restrict__ Yin,
                            int nEdges, int blocksPerDir) {
    int dir = (blockIdx.x >= blocksPerDir) ? 1 : 0;
    int b = blockIdx.x - dir * blocksPerDir;
    int t = b * blockDim.x + threadIdx.x;
    int e = t >> 4;
    if (e >= nEdges) return;
    int sub = (t & 15) * 4;
    int r = erow[e];
    int c = ecol[e];
    float v = eval[e];
    const float* X;
    float* Y;
    int srcN, dstN;
    if (dir == 0) { X = Xout; Y = Yout; srcN = c; dstN = r; }
    else          { X = Xin;  Y = Yin;  srcN = r; dstN = c; }
    float4 x = *reinterpret_cast<const float4*>(X + (size_t)srcN * DFEAT + sub);
    float* yp = Y + (size_t)dstN * DFEAT + sub;
    atomicAdd(yp + 0, v * x.x);
    atomicAdd(yp + 1, v * x.y);
    atomicAdd(yp + 2, v * x.z);
    atomicAdd(yp + 3, v * x.w);
}

// ---------------------------------------------------------------------------
// accum: sum (+)= co*Yout + ci*Yin ; optionally zero next hop's destinations.
// ---------------------------------------------------------------------------
template <int FIRST, int ZERO>
__global__ void accum_kernel(const float* __restrict__ Yout,
                             const float* __restrict__ Yin,
                             float* __restrict__ sum,
                             float* __restrict__ Zout, float* __restrict__ Zin,
                             const float* __restrict__ coefs, int k, int n4) {
    int idx = blockIdx.x * blockDim.x + threadIdx.x;
    if (idx >= n4) return;
    float co = coefs[2 * k];
    float ci = coefs[2 * k + 1];
    float4 yo = reinterpret_cast<const float4*>(Yout)[idx];
    float4 yi = reinterpret_cast<const float4*>(Yin)[idx];
    float4 s;
    if (FIRST) s = make_float4(0.f, 0.f, 0.f, 0.f);
    else       s = reinterpret_cast<const float4*>(sum)[idx];
    s.x += co * yo.x + ci * yi.x;
    s.y += co * yo.y + ci * yi.y;
    s.z += co * yo.z + ci * yi.z;
    s.w += co * yo.w + ci * yi.w;
    reinterpret_cast<float4*>(sum)[idx] = s;
    if (ZERO) {
        float4 z = make_float4(0.f, 0.f, 0.f, 0.f);
        reinterpret_cast<float4*>(Zout)[idx] = z;
        reinterpret_cast<float4*>(Zin)[idx]  = z;
    }
}

// ---------------------------------------------------------------------------
// final: out[r][c] = sigmoid(dot(sum[r,:], Theta[:,c])) + H[r][c]
// sum lives in d_out; in-place safe (block reads its rows before writing).
// ---------------------------------------------------------------------------
__global__ void final_kernel(const float* __restrict__ sum,
                             const float* __restrict__ H,
                             const float* __restrict__ Theta,
                             float* __restrict__ out, int nRows) {
    __shared__ float Th[64][64];     // 16 KB
    __shared__ float Srow[4][64];    // 1 KB
    int t = threadIdx.x;             // 256 threads
    for (int i = t; i < 64 * 64; i += 256) Th[i >> 6][i & 63] = Theta[i];
    int rl = t >> 6;                 // 0..3 local row
    int c = t & 63;                  // 0..63 output col
    int row = blockIdx.x * 4 + rl;
    float sv = (row < nRows) ? sum[(size_t)row * 64 + c] : 0.f;
    Srow[rl][c] = sv;
    __syncthreads();
    if (row >= nRows) return;
    float acc = 0.f;
#pragma unroll
    for (int k = 0; k < 64; ++k) acc += Srow[rl][k] * Th[k][c];
    float sig = 1.0f / (1.0f + __expf(-acc));
    out[(size_t)row * 64 + c] = sig + H[(size_t)row * 64 + c];
}

extern "C" void kernel_launch(void* const* d_in, const int* in_sizes, int n_in,
                              void* d_out, int out_size, void* d_ws, size_t ws_size,
                              hipStream_t stream) {
    const float* H      = (const float*)d_in[0];
    const int*   erow   = (const int*)d_in[1];
    const int*   ecol   = (const int*)d_in[2];
    const float* eval   = (const float*)d_in[3];
    const float* outdeg = (const float*)d_in[4];
    const float* indeg  = (const float*)d_in[5];
    const float* hopatt = (const float*)d_in[6];
    const float* thout  = (const float*)d_in[7];
    const float* thin   = (const float*)d_in[8];
    const float* Theta  = (const float*)d_in[9];
    float* out = (float*)d_out;

    int nNodes = in_sizes[0] / DFEAT;
    int nEdges = in_sizes[1];

    char* ws = (char*)d_ws;
    size_t bufBytes = (size_t)nNodes * DFEAT * sizeof(float);
    float* XAout = (float*)(ws);
    float* XAin  = (float*)(ws + bufBytes);
    float* XBout = (float*)(ws + 2 * bufBytes);
    float* XBin  = (float*)(ws + 3 * bufBytes);
    float* coefs = (float*)(ws + 4 * bufBytes);

    int n4 = nNodes * (DFEAT / 4);          // float4 elements per buffer
    int ewBlocks = (n4 + 255) / 256;

    init_kernel<<<ewBlocks, 256, 0, stream>>>(H, outdeg, indeg, hopatt, thout, thin,
                                              XAout, XAin, XBout, XBin, coefs, n4);

    int bpd = (nEdges * 16 + 255) / 256;    // blocks per direction

    // hop 0: A -> B, accumulate (write) into out, zero A (hop-1 dst)
    spmm_kernel<<<2 * bpd, 256, 0, stream>>>(erow, ecol, eval, XAout, XBout, XAin, XBin,
                                             nEdges, bpd);
    accum_kernel<1, 1><<<ewBlocks, 256, 0, stream>>>(XBout, XBin, out, XAout, XAin,
                                                     coefs, 0, n4);
    // hop 1: B -> A, accumulate, zero B (hop-2 dst)
    spmm_kernel<<<2 * bpd, 256, 0, stream>>>(erow, ecol, eval, XBout, XAout, XBin, XAin,
                                             nEdges, bpd);
    accum_kernel<0, 1><<<ewBlocks, 256, 0, stream>>>(XAout, XAin, out, XBout, XBin,
                                                     coefs, 1, n4);
    // hop 2: A -> B, accumulate only
    spmm_kernel<<<2 * bpd, 256, 0, stream>>>(erow, ecol, eval, XAout, XBout, XAin, XBin,
                                             nEdges, bpd);
    accum_kernel<0, 0><<<ewBlocks, 256, 0, stream>>>(XBout, XBin, out, nullptr, nullptr,
                                                     coefs, 2, n4);

    // final: sigmoid(sum @ Theta) + H, in place on d_out
    final_kernel<<<(nNodes + 3) / 4, 256, 0, stream>>>(out, H, Theta, out, nNodes);
}

// Round 2
// 1415.345 us; speedup vs baseline: 5.7876x; 5.7876x over previous
//
#include <hip/hip_runtime.h>

#define DFEAT 64

// ---------------------------------------------------------------------------
// init: X_out = max(outdeg,1e-8)*H ; X_in = max(indeg,1e-8)*H ;
// zero row/col histogram counters; thread 0 computes softmax(hop_att)*theta.
// ---------------------------------------------------------------------------
__global__ void init_kernel(const float* __restrict__ H,
                            const float* __restrict__ outdeg,
                            const float* __restrict__ indeg,
                            const float* __restrict__ hop_att,
                            const float* __restrict__ th_out,
                            const float* __restrict__ th_in,
                            float* __restrict__ XAout, float* __restrict__ XAin,
                            int* __restrict__ cntR, int* __restrict__ cntC,
                            float* __restrict__ coefs,
                            int n4, int nNodes) {
    int idx = blockIdx.x * blockDim.x + threadIdx.x;
    if (idx == 0) {
        float m = fmaxf(fmaxf(hop_att[0], hop_att[1]), hop_att[2]);
        float e0 = __expf(hop_att[0] - m);
        float e1 = __expf(hop_att[1] - m);
        float e2 = __expf(hop_att[2] - m);
        float inv = 1.0f / (e0 + e1 + e2);
        coefs[0] = e0 * inv * th_out[0]; coefs[1] = e0 * inv * th_in[0];
        coefs[2] = e1 * inv * th_out[1]; coefs[3] = e1 * inv * th_in[1];
        coefs[4] = e2 * inv * th_out[2]; coefs[5] = e2 * inv * th_in[2];
    }
    if (idx <= nNodes) { cntR[idx] = 0; cntC[idx] = 0; }
    if (idx >= n4) return;
    int row = idx >> 4;                       // 16 float4 per 64-wide row
    float4 h = reinterpret_cast<const float4*>(H)[idx];
    float doo = fmaxf(outdeg[row], 1e-8f);
    float dii = fmaxf(indeg[row], 1e-8f);
    reinterpret_cast<float4*>(XAout)[idx] =
        make_float4(h.x * doo, h.y * doo, h.z * doo, h.w * doo);
    reinterpret_cast<float4*>(XAin)[idx] =
        make_float4(h.x * dii, h.y * dii, h.z * dii, h.w * dii);
}

// ---------------------------------------------------------------------------
// histogram of edge endpoints (int atomics, contended ~16x avg — cheap)
// ---------------------------------------------------------------------------
__global__ void hist_kernel(const int* __restrict__ erow,
                            const int* __restrict__ ecol,
                            int* __restrict__ cntR, int* __restrict__ cntC,
                            int nEdges) {
    int e = blockIdx.x * blockDim.x + threadIdx.x;
    if (e >= nEdges) return;
    atomicAdd(&cntR[erow[e]], 1);
    atomicAdd(&cntC[ecol[e]], 1);
}

// ---------------------------------------------------------------------------
// exclusive scan, in place, sequential-carry over 1024-element chunks.
// blockIdx.x = 0 -> row arrays, 1 -> col arrays. Also fills cursor copies
// and ptr[n] = nEdges.
// ---------------------------------------------------------------------------
__global__ void scan_kernel(int* __restrict__ ptrR, int* __restrict__ curR,
                            int* __restrict__ ptrC, int* __restrict__ curC,
                            int n, int nEdges) {
    int* p   = blockIdx.x ? ptrC : ptrR;
    int* cur = blockIdx.x ? curC : curR;
    __shared__ int wsum[16];
    __shared__ int wexcl[16];
    __shared__ int carry;
    __shared__ int tot;
    int t = threadIdx.x;                 // 1024 threads = 16 waves
    int lane = t & 63, wid = t >> 6;
    if (t == 0) carry = 0;
    __syncthreads();
    for (int base = 0; base < n; base += 1024) {
        int i = base + t;
        int v = (i < n) ? p[i] : 0;
        int s = v;                       // inclusive scan within wave
#pragma unroll
        for (int off = 1; off < 64; off <<= 1) {
            int x = __shfl_up(s, off, 64);
            if (lane >= off) s += x;
        }
        if (lane == 63) wsum[wid] = s;
        __syncthreads();
        if (wid == 0 && lane < 16) {     // scan the 16 wave sums
            int w = wsum[lane];
            int si = w;
#pragma unroll
            for (int off = 1; off < 16; off <<= 1) {
                int x = __shfl_up(si, off, 16);
                if ((lane & 15) >= off) si += x;
            }
            wexcl[lane] = si - w;
            if (lane == 15) tot = si;
        }
        __syncthreads();
        int excl = carry + wexcl[wid] + (s - v);
        if (i < n) { p[i] = excl; cur[i] = excl; }
        __syncthreads();
        if (t == 0) carry += tot;
        __syncthreads();
    }
    if (t == 0) p[n] = nEdges;
}

// ---------------------------------------------------------------------------
// scatter edges into CSR (by row: stores col,val) and CSC (by col: stores
// row,val) pair arrays using atomic cursors.
// ---------------------------------------------------------------------------
__global__ void scatter_kernel(const int* __restrict__ erow,
                               const int* __restrict__ ecol,
                               const float* __restrict__ eval,
                               int* __restrict__ curR, int* __restrict__ curC,
                               int2* __restrict__ pairsR, int2* __restrict__ pairsC,
                               int nEdges) {
    int e = blockIdx.x * blockDim.x + threadIdx.x;
    if (e >= nEdges) return;
    int r = erow[e], c = ecol[e];
    int vb = __float_as_int(eval[e]);
    int pR = atomicAdd(&curR[r], 1);
    pairsR[pR] = make_int2(c, vb);
    int pC = atomicAdd(&curC[c], 1);
    pairsC[pC] = make_int2(r, vb);
}

// ---------------------------------------------------------------------------
// fused spmm, both directions + hop accumulation. One 64-lane wave per node,
// lane = feature dim. No atomics.
//   accO[node][lane] = sum_{(node,c) in CSR} val * Xout[c][lane]
//   accI[node][lane] = sum_{(r,node) in CSC} val * Xin [r][lane]
//   sum (+)= co*accO + ci*accI ; Yout/Yin written unless LAST.
// ---------------------------------------------------------------------------
template <int FIRST, int LAST>
__global__ __launch_bounds__(256) void spmm_fused(
        const int* __restrict__ rowptr, const int2* __restrict__ pairsR,
        const int* __restrict__ colptr, const int2* __restrict__ pairsC,
        const float* __restrict__ Xout, const float* __restrict__ Xin,
        float* __restrict__ Yout, float* __restrict__ Yin,
        float* __restrict__ sum, const float* __restrict__ coefs,
        int k, int nNodes) {
    int node = blockIdx.x * (blockDim.x >> 6) + (threadIdx.x >> 6);
    if (node >= nNodes) return;
    int lane = threadIdx.x & 63;
    float co = coefs[2 * k], ci = coefs[2 * k + 1];
    float accO = 0.f, accI = 0.f;
    int b = rowptr[node], e = rowptr[node + 1];
    for (int j = b; j < e; ++j) {
        int2 p = pairsR[j];
        accO += __int_as_float(p.y) * Xout[p.x * DFEAT + lane];
    }
    b = colptr[node]; e = colptr[node + 1];
    for (int j = b; j < e; ++j) {
        int2 p = pairsC[j];
        accI += __int_as_float(p.y) * Xin[p.x * DFEAT + lane];
    }
    int off = node * DFEAT + lane;
    if (!LAST) { Yout[off] = accO; Yin[off] = accI; }
    float s = co * accO + ci * accI;
    if (FIRST) sum[off] = s;
    else       sum[off] += s;
}

// ---------------------------------------------------------------------------
// final: out[r][c] = sigmoid(dot(sum[r,:], Theta[:,c])) + H[r][c]
// sum lives in d_out; in-place safe (block reads its rows before writing).
// ---------------------------------------------------------------------------
__global__ void final_kernel(const float* __restrict__ sum,
                             const float* __restrict__ H,
                             const float* __restrict__ Theta,
                             float* __restrict__ out, int nRows) {
    __shared__ float Th[64][64];
    __shared__ float Srow[4][64];
    int t = threadIdx.x;             // 256 threads
    for (int i = t; i < 64 * 64; i += 256) Th[i >> 6][i & 63] = Theta[i];
    int rl = t >> 6;
    int c = t & 63;
    int row = blockIdx.x * 4 + rl;
    float sv = (row < nRows) ? sum[(size_t)row * 64 + c] : 0.f;
    Srow[rl][c] = sv;
    __syncthreads();
    if (row >= nRows) return;
    float acc = 0.f;
#pragma unroll
    for (int kk = 0; kk < 64; ++kk) acc += Srow[rl][kk] * Th[kk][c];
    float sig = 1.0f / (1.0f + __expf(-acc));
    out[(size_t)row * 64 + c] = sig + H[(size_t)row * 64 + c];
}

extern "C" void kernel_launch(void* const* d_in, const int* in_sizes, int n_in,
                              void* d_out, int out_size, void* d_ws, size_t ws_size,
                              hipStream_t stream) {
    const float* H      = (const float*)d_in[0];
    const int*   erow   = (const int*)d_in[1];
    const int*   ecol   = (const int*)d_in[2];
    const float* eval   = (const float*)d_in[3];
    const float* outdeg = (const float*)d_in[4];
    const float* indeg  = (const float*)d_in[5];
    const float* hopatt = (const float*)d_in[6];
    const float* thout  = (const float*)d_in[7];
    const float* thin   = (const float*)d_in[8];
    const float* Theta  = (const float*)d_in[9];
    float* out = (float*)d_out;

    int nNodes = in_sizes[0] / DFEAT;
    int nEdges = in_sizes[1];

    char* ws = (char*)d_ws;
    size_t off = 0;
    auto alloc = [&](size_t bytes) {
        void* p = ws + off;
        off += (bytes + 255) & ~(size_t)255;
        return p;
    };
    size_t bufBytes = (size_t)nNodes * DFEAT * sizeof(float);
    float* XAout = (float*)alloc(bufBytes);
    float* XAin  = (float*)alloc(bufBytes);
    float* XBout = (float*)alloc(bufBytes);
    float* XBin  = (float*)alloc(bufBytes);
    int*   rowptr = (int*)alloc((size_t)(nNodes + 1) * sizeof(int));
    int*   colptr = (int*)alloc((size_t)(nNodes + 1) * sizeof(int));
    int*   curR   = (int*)alloc((size_t)nNodes * sizeof(int));
    int*   curC   = (int*)alloc((size_t)nNodes * sizeof(int));
    int2*  pairsR = (int2*)alloc((size_t)nEdges * sizeof(int2));
    int2*  pairsC = (int2*)alloc((size_t)nEdges * sizeof(int2));
    float* coefs  = (float*)alloc(8 * sizeof(float));

    int n4 = nNodes * (DFEAT / 4);
    int ewBlocks = (n4 + 255) / 256;
    int eBlocks = (nEdges + 255) / 256;
    int nodeBlocks = (nNodes + 3) / 4;       // 4 waves per 256-thread block

    // ---- build phase ----
    init_kernel<<<ewBlocks, 256, 0, stream>>>(H, outdeg, indeg, hopatt, thout, thin,
                                              XAout, XAin, rowptr, colptr, coefs,
                                              n4, nNodes);
    hist_kernel<<<eBlocks, 256, 0, stream>>>(erow, ecol, rowptr, colptr, nEdges);
    scan_kernel<<<2, 1024, 0, stream>>>(rowptr, curR, colptr, curC, nNodes, nEdges);
    scatter_kernel<<<eBlocks, 256, 0, stream>>>(erow, ecol, eval, curR, curC,
                                                pairsR, pairsC, nEdges);

    // ---- hop phase (sum accumulates in d_out) ----
    spmm_fused<1, 0><<<nodeBlocks, 256, 0, stream>>>(rowptr, pairsR, colptr, pairsC,
                                                     XAout, XAin, XBout, XBin,
                                                     out, coefs, 0, nNodes);
    spmm_fused<0, 0><<<nodeBlocks, 256, 0, stream>>>(rowptr, pairsR, colptr, pairsC,
                                                     XBout, XBin, XAout, XAin,
                                                     out, coefs, 1, nNodes);
    spmm_fused<0, 1><<<nodeBlocks, 256, 0, stream>>>(rowptr, pairsR, colptr, pairsC,
                                                     XAout, XAin, nullptr, nullptr,
                                                     out, coefs, 2, nNodes);

    // ---- final: sigmoid(sum @ Theta) + H, in place on d_out ----
    final_kernel<<<(nNodes + 3) / 4, 256, 0, stream>>>(out, H, Theta, out, nNodes);
}

// Round 3
// 1390.096 us; speedup vs baseline: 5.8928x; 1.0182x over previous
//
#include <hip/hip_runtime.h>

#define DFEAT 64
#define BUCKET_SHIFT 8          // 256 nodes per scatter bucket

__device__ __forceinline__ unsigned short f2bf(float f) {
    unsigned u = __float_as_uint(f);
    u += 0x7FFFu + ((u >> 16) & 1u);        // round-to-nearest-even
    return (unsigned short)(u >> 16);
}
__device__ __forceinline__ float bf2f(unsigned short h) {
    return __uint_as_float((unsigned)h << 16);
}

// ---------------------------------------------------------------------------
// init: X_out = bf16(max(outdeg,1e-8)*H) ; X_in = bf16(max(indeg,1e-8)*H) ;
// zero histogram counters; thread 0 computes softmax(hop_att)*theta coefs.
// ---------------------------------------------------------------------------
__global__ void init_kernel(const float* __restrict__ H,
                            const float* __restrict__ outdeg,
                            const float* __restrict__ indeg,
                            const float* __restrict__ hop_att,
                            const float* __restrict__ th_out,
                            const float* __restrict__ th_in,
                            unsigned short* __restrict__ XAout,
                            unsigned short* __restrict__ XAin,
                            int* __restrict__ cntR, int* __restrict__ cntC,
                            float* __restrict__ coefs,
                            int n4, int nNodes) {
    int idx = blockIdx.x * blockDim.x + threadIdx.x;
    if (idx == 0) {
        float m = fmaxf(fmaxf(hop_att[0], hop_att[1]), hop_att[2]);
        float e0 = __expf(hop_att[0] - m);
        float e1 = __expf(hop_att[1] - m);
        float e2 = __expf(hop_att[2] - m);
        float inv = 1.0f / (e0 + e1 + e2);
        coefs[0] = e0 * inv * th_out[0]; coefs[1] = e0 * inv * th_in[0];
        coefs[2] = e1 * inv * th_out[1]; coefs[3] = e1 * inv * th_in[1];
        coefs[4] = e2 * inv * th_out[2]; coefs[5] = e2 * inv * th_in[2];
    }
    if (idx <= nNodes) { cntR[idx] = 0; cntC[idx] = 0; }
    if (idx >= n4) return;
    int row = idx >> 4;                       // 16 float4 per 64-wide row
    float4 h = reinterpret_cast<const float4*>(H)[idx];
    float doo = fmaxf(outdeg[row], 1e-8f);
    float dii = fmaxf(indeg[row], 1e-8f);
    reinterpret_cast<ushort4*>(XAout)[idx] =
        make_ushort4(f2bf(h.x * doo), f2bf(h.y * doo), f2bf(h.z * doo), f2bf(h.w * doo));
    reinterpret_cast<ushort4*>(XAin)[idx] =
        make_ushort4(f2bf(h.x * dii), f2bf(h.y * dii), f2bf(h.z * dii), f2bf(h.w * dii));
}

// ---------------------------------------------------------------------------
// histogram of edge endpoints
// ---------------------------------------------------------------------------
__global__ void hist_kernel(const int* __restrict__ erow,
                            const int* __restrict__ ecol,
                            int* __restrict__ cntR, int* __restrict__ cntC,
                            int nEdges) {
    int e = blockIdx.x * blockDim.x + threadIdx.x;
    if (e >= nEdges) return;
    atomicAdd(&cntR[erow[e]], 1);
    atomicAdd(&cntC[ecol[e]], 1);
}

// ---------------------------------------------------------------------------
// hierarchical exclusive scan: reduce -> spine -> downsweep
// chunk = 1024 elements per block (256 threads x 4).
// ---------------------------------------------------------------------------
__global__ void scan_reduce(const int* __restrict__ cntR,
                            const int* __restrict__ cntC,
                            int* __restrict__ bsum, int n, int nChunks) {
    int dir = (blockIdx.x >= nChunks) ? 1 : 0;
    int ch = blockIdx.x - dir * nChunks;
    const int* p = dir ? cntC : cntR;
    int t = threadIdx.x, lane = t & 63, wid = t >> 6;
    int base = ch * 1024 + t * 4;
    int s = 0;
#pragma unroll
    for (int i = 0; i < 4; ++i) { int idx = base + i; if (idx < n) s += p[idx]; }
#pragma unroll
    for (int off = 32; off >= 1; off >>= 1) s += __shfl_down(s, off, 64);
    __shared__ int wsum[4];
    if (lane == 0) wsum[wid] = s;
    __syncthreads();
    if (t == 0) bsum[dir * nChunks + ch] = wsum[0] + wsum[1] + wsum[2] + wsum[3];
}

__global__ void scan_spine(int* __restrict__ bsum, int nChunks) {
    int* p = bsum + blockIdx.x * nChunks;     // blockIdx = direction
    int lane = threadIdx.x;                    // single 64-lane wave
    int carry = 0;
    for (int base = 0; base < nChunks; base += 64) {
        int i = base + lane;
        int v = (i < nChunks) ? p[i] : 0;
        int s = v;
#pragma unroll
        for (int off = 1; off < 64; off <<= 1) {
            int x = __shfl_up(s, off, 64);
            if (lane >= off) s += x;
        }
        if (i < nChunks) p[i] = carry + s - v;
        carry += __shfl(s, 63, 64);
    }
}

__global__ void scan_down(int* __restrict__ cntR, int* __restrict__ curR,
                          int* __restrict__ cntC, int* __restrict__ curC,
                          const int* __restrict__ bsum,
                          int n, int nChunks, int nEdges) {
    int dir = (blockIdx.x >= nChunks) ? 1 : 0;
    int ch = blockIdx.x - dir * nChunks;
    int* p = dir ? cntC : cntR;
    int* cur = dir ? curC : curR;
    int t = threadIdx.x, lane = t & 63, wid = t >> 6;
    int base = ch * 1024 + t * 4;
    int v[4];
    int tsum = 0;
#pragma unroll
    for (int i = 0; i < 4; ++i) {
        v[i] = (base + i < n) ? p[base + i] : 0;
        tsum += v[i];
    }
    int inc = tsum;
#pragma unroll
    for (int off = 1; off < 64; off <<= 1) {
        int x = __shfl_up(inc, off, 64);
        if (lane >= off) inc += x;
    }
    __shared__ int wsum[4];
    if (lane == 63) wsum[wid] = inc;
    __syncthreads();
    int woff = 0;
    for (int w = 0; w < wid; ++w) woff += wsum[w];
    int run = bsum[dir * nChunks + ch] + woff + inc - tsum;
#pragma unroll
    for (int i = 0; i < 4; ++i) {
        if (base + i < n) { p[base + i] = run; cur[base + i] = run; }
        run += v[i];
    }
    if (ch == nChunks - 1 && t == 0) p[n] = nEdges;
}

// ---------------------------------------------------------------------------
// bucket cursor init: bucket b's region starts at ptr[b<<BUCKET_SHIFT]
// ---------------------------------------------------------------------------
__global__ void bucket_init(const int* __restrict__ rowptr,
                            const int* __restrict__ colptr,
                            int* __restrict__ bcurR, int* __restrict__ bcurC,
                            int nB, int n) {
    int b = blockIdx.x * blockDim.x + threadIdx.x;
    if (b >= nB) return;
    int s = b << BUCKET_SHIFT;
    if (s > n) s = n;
    bcurR[b] = rowptr[s];
    bcurC[b] = colptr[s];
}

// ---------------------------------------------------------------------------
// Pass A: bin edges by 256-node bucket. Writes stream sequentially within
// each bucket region (full-line write-combine).
// ---------------------------------------------------------------------------
__global__ void bucket_scatter(const int* __restrict__ erow,
                               const int* __restrict__ ecol,
                               const float* __restrict__ eval,
                               int* __restrict__ bcurR, int* __restrict__ bcurC,
                               int* __restrict__ bufRkey, int2* __restrict__ bufRpay,
                               int* __restrict__ bufCkey, int2* __restrict__ bufCpay,
                               int nEdges) {
    int e = blockIdx.x * blockDim.x + threadIdx.x;
    if (e >= nEdges) return;
    int r = erow[e], c = ecol[e];
    int vb = __float_as_int(eval[e]);
    int pR = atomicAdd(&bcurR[r >> BUCKET_SHIFT], 1);
    bufRkey[pR] = r; bufRpay[pR] = make_int2(c, vb);
    int pC = atomicAdd(&bcurC[c >> BUCKET_SHIFT], 1);
    bufCkey[pC] = c; bufCpay[pC] = make_int2(r, vb);
}

// ---------------------------------------------------------------------------
// Pass B: within-bucket scatter to exact CSR/CSC slots. Reads are sequential;
// writes land inside the bucket's ~32KB window (L2-resident, no partial-line
// amplification).
// ---------------------------------------------------------------------------
__global__ void final_scatter(const int* __restrict__ bufRkey,
                              const int2* __restrict__ bufRpay,
                              const int* __restrict__ bufCkey,
                              const int2* __restrict__ bufCpay,
                              int* __restrict__ curR, int* __restrict__ curC,
                              int2* __restrict__ pairsR, int2* __restrict__ pairsC,
                              int nEdges) {
    int s = blockIdx.x * blockDim.x + threadIdx.x;
    if (s >= nEdges) return;
    int r = bufRkey[s];
    int pR = atomicAdd(&curR[r], 1);
    pairsR[pR] = bufRpay[s];
    int c = bufCkey[s];
    int pC = atomicAdd(&curC[c], 1);
    pairsC[pC] = bufCpay[s];
}

// ---------------------------------------------------------------------------
// fused spmm, both directions + hop accumulation. One 64-lane wave per node,
// lane = feature dim. X/Y in bf16 (halves gather traffic); sum in f32.
// ---------------------------------------------------------------------------
template <int FIRST, int LAST>
__global__ __launch_bounds__(256) void spmm_fused(
        const int* __restrict__ rowptr, const int2* __restrict__ pairsR,
        const int* __restrict__ colptr, const int2* __restrict__ pairsC,
        const unsigned short* __restrict__ Xout,
        const unsigned short* __restrict__ Xin,
        unsigned short* __restrict__ Yout, unsigned short* __restrict__ Yin,
        float* __restrict__ sum, const float* __restrict__ coefs,
        int k, int nNodes) {
    int node = blockIdx.x * (blockDim.x >> 6) + (threadIdx.x >> 6);
    if (node >= nNodes) return;
    int lane = threadIdx.x & 63;
    float co = coefs[2 * k], ci = coefs[2 * k + 1];
    float accO = 0.f, accO1 = 0.f, accI = 0.f, accI1 = 0.f;

    int b = rowptr[node], e = rowptr[node + 1];
    int j = b;
    for (; j + 2 <= e; j += 2) {
        int2 p0 = pairsR[j];
        int2 p1 = pairsR[j + 1];
        float x0 = bf2f(Xout[p0.x * DFEAT + lane]);
        float x1 = bf2f(Xout[p1.x * DFEAT + lane]);
        accO  += __int_as_float(p0.y) * x0;
        accO1 += __int_as_float(p1.y) * x1;
    }
    if (j < e) {
        int2 p = pairsR[j];
        accO += __int_as_float(p.y) * bf2f(Xout[p.x * DFEAT + lane]);
    }
    accO += accO1;

    b = colptr[node]; e = colptr[node + 1];
    j = b;
    for (; j + 2 <= e; j += 2) {
        int2 p0 = pairsC[j];
        int2 p1 = pairsC[j + 1];
        float x0 = bf2f(Xin[p0.x * DFEAT + lane]);
        float x1 = bf2f(Xin[p1.x * DFEAT + lane]);
        accI  += __int_as_float(p0.y) * x0;
        accI1 += __int_as_float(p1.y) * x1;
    }
    if (j < e) {
        int2 p = pairsC[j];
        accI += __int_as_float(p.y) * bf2f(Xin[p.x * DFEAT + lane]);
    }
    accI += accI1;

    int off = node * DFEAT + lane;
    if (!LAST) { Yout[off] = f2bf(accO); Yin[off] = f2bf(accI); }
    float s = co * accO + ci * accI;
    if (FIRST) sum[off] = s;
    else       sum[off] += s;
}

// ---------------------------------------------------------------------------
// final: out[r][c] = sigmoid(dot(sum[r,:], Theta[:,c])) + H[r][c]
// sum lives in d_out; in-place safe (block reads its rows before writing).
// ---------------------------------------------------------------------------
__global__ void final_kernel(const float* __restrict__ sum,
                             const float* __restrict__ H,
                             const float* __restrict__ Theta,
                             float* __restrict__ out, int nRows) {
    __shared__ float Th[64][64];
    __shared__ float Srow[4][64];
    int t = threadIdx.x;             // 256 threads
    for (int i = t; i < 64 * 64; i += 256) Th[i >> 6][i & 63] = Theta[i];
    int rl = t >> 6;
    int c = t & 63;
    int row = blockIdx.x * 4 + rl;
    float sv = (row < nRows) ? sum[(size_t)row * 64 + c] : 0.f;
    Srow[rl][c] = sv;
    __syncthreads();
    if (row >= nRows) return;
    float acc = 0.f;
#pragma unroll
    for (int kk = 0; kk < 64; ++kk) acc += Srow[rl][kk] * Th[kk][c];
    float sig = 1.0f / (1.0f + __expf(-acc));
    out[(size_t)row * 64 + c] = sig + H[(size_t)row * 64 + c];
}

extern "C" void kernel_launch(void* const* d_in, const int* in_sizes, int n_in,
                              void* d_out, int out_size, void* d_ws, size_t ws_size,
                              hipStream_t stream) {
    const float* H      = (const float*)d_in[0];
    const int*   erow   = (const int*)d_in[1];
    const int*   ecol   = (const int*)d_in[2];
    const float* eval   = (const float*)d_in[3];
    const float* outdeg = (const float*)d_in[4];
    const float* indeg  = (const float*)d_in[5];
    const float* hopatt = (const float*)d_in[6];
    const float* thout  = (const float*)d_in[7];
    const float* thin   = (const float*)d_in[8];
    const float* Theta  = (const float*)d_in[9];
    float* out = (float*)d_out;

    int nNodes = in_sizes[0] / DFEAT;
    int nEdges = in_sizes[1];

    char* ws = (char*)d_ws;
    size_t off = 0;
    auto alloc = [&](size_t bytes) {
        void* p = ws + off;
        off += (bytes + 255) & ~(size_t)255;
        return p;
    };
    size_t xBytes = (size_t)nNodes * DFEAT * sizeof(unsigned short);
    unsigned short* XAout = (unsigned short*)alloc(xBytes);
    unsigned short* XAin  = (unsigned short*)alloc(xBytes);
    unsigned short* XBout = (unsigned short*)alloc(xBytes);
    unsigned short* XBin  = (unsigned short*)alloc(xBytes);
    int*   rowptr = (int*)alloc((size_t)(nNodes + 1) * sizeof(int));
    int*   colptr = (int*)alloc((size_t)(nNodes + 1) * sizeof(int));
    int*   curR   = (int*)alloc((size_t)nNodes * sizeof(int));
    int*   curC   = (int*)alloc((size_t)nNodes * sizeof(int));
    int2*  pairsR = (int2*)alloc((size_t)nEdges * sizeof(int2));
    int2*  pairsC = (int2*)alloc((size_t)nEdges * sizeof(int2));
    int*   bufRkey = (int*)alloc((size_t)nEdges * sizeof(int));
    int2*  bufRpay = (int2*)alloc((size_t)nEdges * sizeof(int2));
    int*   bufCkey = (int*)alloc((size_t)nEdges * sizeof(int));
    int2*  bufCpay = (int2*)alloc((size_t)nEdges * sizeof(int2));
    int nChunks = (nNodes + 1023) / 1024;
    int*   bsum  = (int*)alloc((size_t)(2 * nChunks) * sizeof(int));
    int nB = (nNodes + (1 << BUCKET_SHIFT) - 1) >> BUCKET_SHIFT;
    int*   bcurR = (int*)alloc((size_t)nB * sizeof(int));
    int*   bcurC = (int*)alloc((size_t)nB * sizeof(int));
    float* coefs = (float*)alloc(8 * sizeof(float));

    int n4 = nNodes * (DFEAT / 4);
    int ewBlocks = (n4 + 255) / 256;
    int eBlocks = (nEdges + 255) / 256;
    int nodeBlocks = (nNodes + 3) / 4;       // 4 waves per 256-thread block

    // ---- build phase ----
    init_kernel<<<ewBlocks, 256, 0, stream>>>(H, outdeg, indeg, hopatt, thout, thin,
                                              XAout, XAin, rowptr, colptr, coefs,
                                              n4, nNodes);
    hist_kernel<<<eBlocks, 256, 0, stream>>>(erow, ecol, rowptr, colptr, nEdges);
    scan_reduce<<<2 * nChunks, 256, 0, stream>>>(rowptr, colptr, bsum, nNodes, nChunks);
    scan_spine<<<2, 64, 0, stream>>>(bsum, nChunks);
    scan_down<<<2 * nChunks, 256, 0, stream>>>(rowptr, curR, colptr, curC, bsum,
                                               nNodes, nChunks, nEdges);
    bucket_init<<<(nB + 255) / 256, 256, 0, stream>>>(rowptr, colptr, bcurR, bcurC,
                                                      nB, nNodes);
    bucket_scatter<<<eBlocks, 256, 0, stream>>>(erow, ecol, eval, bcurR, bcurC,
                                                bufRkey, bufRpay, bufCkey, bufCpay,
                                                nEdges);
    final_scatter<<<eBlocks, 256, 0, stream>>>(bufRkey, bufRpay, bufCkey, bufCpay,
                                               curR, curC, pairsR, pairsC, nEdges);

    // ---- hop phase (sum accumulates in d_out) ----
    spmm_fused<1, 0><<<nodeBlocks, 256, 0, stream>>>(rowptr, pairsR, colptr, pairsC,
                                                     XAout, XAin, XBout, XBin,
                                                     out, coefs, 0, nNodes);
    spmm_fused<0, 0><<<nodeBlocks, 256, 0, stream>>>(rowptr, pairsR, colptr, pairsC,
                                                     XBout, XBin, XAout, XAin,
                                                     out, coefs, 1, nNodes);
    spmm_fused<0, 1><<<nodeBlocks, 256, 0, stream>>>(rowptr, pairsR, colptr, pairsC,
                                                     XAout, XAin, nullptr, nullptr,
                                                     out, coefs, 2, nNodes);

    // ---- final: sigmoid(sum @ Theta) + H, in place on d_out ----
    final_kernel<<<(nNodes + 3) / 4, 256, 0, stream>>>(out, H, Theta, out, nNodes);
}

// Round 4
// 825.285 us; speedup vs baseline: 9.9257x; 1.6844x over previous
//
#include <hip/hip_runtime.h>

#define DFEAT 64

__device__ __forceinline__ unsigned short f2bf(float f) {
    unsigned u = __float_as_uint(f);
    u += 0x7FFFu + ((u >> 16) & 1u);        // round-to-nearest-even
    return (unsigned short)(u >> 16);
}
__device__ __forceinline__ float bf2f(unsigned short h) {
    return __uint_as_float((unsigned)h << 16);
}

// ---------------------------------------------------------------------------
// fused init + histogram (same grid size: n4 == nEdges == 1.6M here).
// Counters must be pre-zeroed via hipMemsetAsync.
// ---------------------------------------------------------------------------
__global__ void init_hist(const float* __restrict__ H,
                          const float* __restrict__ outdeg,
                          const float* __restrict__ indeg,
                          const float* __restrict__ hop_att,
                          const float* __restrict__ th_out,
                          const float* __restrict__ th_in,
                          const int* __restrict__ erow,
                          const int* __restrict__ ecol,
                          unsigned short* __restrict__ XAout,
                          unsigned short* __restrict__ XAin,
                          int* __restrict__ cntR, int* __restrict__ cntC,
                          float* __restrict__ coefs,
                          int n4, int nEdges) {
    int idx = blockIdx.x * blockDim.x + threadIdx.x;
    if (idx == 0) {
        float m = fmaxf(fmaxf(hop_att[0], hop_att[1]), hop_att[2]);
        float e0 = __expf(hop_att[0] - m);
        float e1 = __expf(hop_att[1] - m);
        float e2 = __expf(hop_att[2] - m);
        float inv = 1.0f / (e0 + e1 + e2);
        coefs[0] = e0 * inv * th_out[0]; coefs[1] = e0 * inv * th_in[0];
        coefs[2] = e1 * inv * th_out[1]; coefs[3] = e1 * inv * th_in[1];
        coefs[4] = e2 * inv * th_out[2]; coefs[5] = e2 * inv * th_in[2];
    }
    if (idx < n4) {
        int row = idx >> 4;                   // 16 float4 per 64-wide row
        float4 h = reinterpret_cast<const float4*>(H)[idx];
        float doo = fmaxf(outdeg[row], 1e-8f);
        float dii = fmaxf(indeg[row], 1e-8f);
        reinterpret_cast<ushort4*>(XAout)[idx] =
            make_ushort4(f2bf(h.x * doo), f2bf(h.y * doo), f2bf(h.z * doo), f2bf(h.w * doo));
        reinterpret_cast<ushort4*>(XAin)[idx] =
            make_ushort4(f2bf(h.x * dii), f2bf(h.y * dii), f2bf(h.z * dii), f2bf(h.w * dii));
    }
    if (idx < nEdges) {
        atomicAdd(&cntR[erow[idx]], 1);
        atomicAdd(&cntC[ecol[idx]], 1);
    }
}

// ---------------------------------------------------------------------------
// hierarchical exclusive scan: reduce -> spine -> downsweep
// ---------------------------------------------------------------------------
__global__ void scan_reduce(const int* __restrict__ cntR,
                            const int* __restrict__ cntC,
                            int* __restrict__ bsum, int n, int nChunks) {
    int dir = (blockIdx.x >= nChunks) ? 1 : 0;
    int ch = blockIdx.x - dir * nChunks;
    const int* p = dir ? cntC : cntR;
    int t = threadIdx.x, lane = t & 63, wid = t >> 6;
    int base = ch * 1024 + t * 4;
    int s = 0;
#pragma unroll
    for (int i = 0; i < 4; ++i) { int idx = base + i; if (idx < n) s += p[idx]; }
#pragma unroll
    for (int off = 32; off >= 1; off >>= 1) s += __shfl_down(s, off, 64);
    __shared__ int wsum[4];
    if (lane == 0) wsum[wid] = s;
    __syncthreads();
    if (t == 0) bsum[dir * nChunks + ch] = wsum[0] + wsum[1] + wsum[2] + wsum[3];
}

__global__ void scan_spine(int* __restrict__ bsum, int nChunks) {
    int* p = bsum + blockIdx.x * nChunks;     // blockIdx = direction
    int lane = threadIdx.x;                    // single 64-lane wave
    int carry = 0;
    for (int base = 0; base < nChunks; base += 64) {
        int i = base + lane;
        int v = (i < nChunks) ? p[i] : 0;
        int s = v;
#pragma unroll
        for (int off = 1; off < 64; off <<= 1) {
            int x = __shfl_up(s, off, 64);
            if (lane >= off) s += x;
        }
        if (i < nChunks) p[i] = carry + s - v;
        carry += __shfl(s, 63, 64);
    }
}

__global__ void scan_down(int* __restrict__ cntR, int* __restrict__ curR,
                          int* __restrict__ cntC, int* __restrict__ curC,
                          const int* __restrict__ bsum,
                          int n, int nChunks, int nEdges) {
    int dir = (blockIdx.x >= nChunks) ? 1 : 0;
    int ch = blockIdx.x - dir * nChunks;
    int* p = dir ? cntC : cntR;
    int* cur = dir ? curC : curR;
    int t = threadIdx.x, lane = t & 63, wid = t >> 6;
    int base = ch * 1024 + t * 4;
    int v[4];
    int tsum = 0;
#pragma unroll
    for (int i = 0; i < 4; ++i) {
        v[i] = (base + i < n) ? p[base + i] : 0;
        tsum += v[i];
    }
    int inc = tsum;
#pragma unroll
    for (int off = 1; off < 64; off <<= 1) {
        int x = __shfl_up(inc, off, 64);
        if (lane >= off) inc += x;
    }
    __shared__ int wsum[4];
    if (lane == 63) wsum[wid] = inc;
    __syncthreads();
    int woff = 0;
    for (int w = 0; w < wid; ++w) woff += wsum[w];
    int run = bsum[dir * nChunks + ch] + woff + inc - tsum;
#pragma unroll
    for (int i = 0; i < 4; ++i) {
        if (base + i < n) { p[base + i] = run; cur[base + i] = run; }
        run += v[i];
    }
    if (ch == nChunks - 1 && t == 0) p[n] = nEdges;
}

// ---------------------------------------------------------------------------
// direct scatter into CSR (col,val by row) and CSC (row,val by col).
// Per-node cursors: ~16-deep contention, 100K parallel chains — fast.
// ---------------------------------------------------------------------------
__global__ void scatter_kernel(const int* __restrict__ erow,
                               const int* __restrict__ ecol,
                               const float* __restrict__ eval,
                               int* __restrict__ curR, int* __restrict__ curC,
                               int2* __restrict__ pairsR, int2* __restrict__ pairsC,
                               int nEdges) {
    int e = blockIdx.x * blockDim.x + threadIdx.x;
    if (e >= nEdges) return;
    int r = erow[e], c = ecol[e];
    int vb = __float_as_int(eval[e]);
    int pR = atomicAdd(&curR[r], 1);
    pairsR[pR] = make_int2(c, vb);
    int pC = atomicAdd(&curC[c], 1);
    pairsC[pC] = make_int2(r, vb);
}

// ---------------------------------------------------------------------------
// fused spmm, both directions + hop accumulation. One 64-lane wave per node,
// lane = feature dim. X/Y bf16, sum f32. 4x unrolled gather for MLP.
// LAST variant fuses sigmoid(sum @ Theta) + H epilogue (Theta in LDS,
// per-wave LDS row for the cross-lane dot). No early return when LAST.
// ---------------------------------------------------------------------------
template <int FIRST, int LAST>
__global__ __launch_bounds__(256) void spmm_fused(
        const int* __restrict__ rowptr, const int2* __restrict__ pairsR,
        const int* __restrict__ colptr, const int2* __restrict__ pairsC,
        const unsigned short* __restrict__ Xout,
        const unsigned short* __restrict__ Xin,
        unsigned short* __restrict__ Yout, unsigned short* __restrict__ Yin,
        float* __restrict__ sum,
        const float* __restrict__ H, const float* __restrict__ Theta,
        const float* __restrict__ coefs,
        int k, int nNodes) {
    __shared__ float Th[LAST ? 64 * 64 : 1];
    __shared__ float Srow[LAST ? 4 * 64 : 1];
    int wid = threadIdx.x >> 6;
    int lane = threadIdx.x & 63;
    int node = blockIdx.x * 4 + wid;
    bool live = node < nNodes;
    if (!LAST && !live) return;
    int nodeC = live ? node : 0;

    if (LAST) {                       // issue Theta->LDS early; barrier later
        for (int i = threadIdx.x; i < 64 * 64; i += 256) Th[i] = Theta[i];
    }

    float co = coefs[2 * k], ci = coefs[2 * k + 1];
    float a0 = 0.f, a1 = 0.f, a2 = 0.f, a3 = 0.f;
    int b = rowptr[nodeC], e = rowptr[nodeC + 1];
    int j = b;
    for (; j + 4 <= e; j += 4) {
        int2 p0 = pairsR[j];
        int2 p1 = pairsR[j + 1];
        int2 p2 = pairsR[j + 2];
        int2 p3 = pairsR[j + 3];
        float x0 = bf2f(Xout[p0.x * DFEAT + lane]);
        float x1 = bf2f(Xout[p1.x * DFEAT + lane]);
        float x2 = bf2f(Xout[p2.x * DFEAT + lane]);
        float x3 = bf2f(Xout[p3.x * DFEAT + lane]);
        a0 += __int_as_float(p0.y) * x0;
        a1 += __int_as_float(p1.y) * x1;
        a2 += __int_as_float(p2.y) * x2;
        a3 += __int_as_float(p3.y) * x3;
    }
    for (; j < e; ++j) {
        int2 p = pairsR[j];
        a0 += __int_as_float(p.y) * bf2f(Xout[p.x * DFEAT + lane]);
    }
    float accO = (a0 + a1) + (a2 + a3);

    a0 = a1 = a2 = a3 = 0.f;
    b = colptr[nodeC]; e = colptr[nodeC + 1];
    j = b;
    for (; j + 4 <= e; j += 4) {
        int2 p0 = pairsC[j];
        int2 p1 = pairsC[j + 1];
        int2 p2 = pairsC[j + 2];
        int2 p3 = pairsC[j + 3];
        float x0 = bf2f(Xin[p0.x * DFEAT + lane]);
        float x1 = bf2f(Xin[p1.x * DFEAT + lane]);
        float x2 = bf2f(Xin[p2.x * DFEAT + lane]);
        float x3 = bf2f(Xin[p3.x * DFEAT + lane]);
        a0 += __int_as_float(p0.y) * x0;
        a1 += __int_as_float(p1.y) * x1;
        a2 += __int_as_float(p2.y) * x2;
        a3 += __int_as_float(p3.y) * x3;
    }
    for (; j < e; ++j) {
        int2 p = pairsC[j];
        a0 += __int_as_float(p.y) * bf2f(Xin[p.x * DFEAT + lane]);
    }
    float accI = (a0 + a1) + (a2 + a3);

    int off = nodeC * DFEAT + lane;
    if (!LAST) {
        Yout[off] = f2bf(accO);
        Yin[off] = f2bf(accI);
        float s = co * accO + ci * accI;
        if (FIRST) sum[off] = s;
        else       sum[off] += s;
    } else {
        float s = sum[off] + co * accO + ci * accI;   // final sum_term row
        __syncthreads();                               // Theta visible
        Srow[wid * 64 + lane] = s;                     // wave-local staging
        float acc = 0.f;
#pragma unroll
        for (int kk = 0; kk < 64; ++kk)
            acc += Srow[wid * 64 + kk] * Th[kk * 64 + lane];
        if (live)
            sum[off] = 1.0f / (1.0f + __expf(-acc)) + H[off];
    }
}

extern "C" void kernel_launch(void* const* d_in, const int* in_sizes, int n_in,
                              void* d_out, int out_size, void* d_ws, size_t ws_size,
                              hipStream_t stream) {
    const float* H      = (const float*)d_in[0];
    const int*   erow   = (const int*)d_in[1];
    const int*   ecol   = (const int*)d_in[2];
    const float* eval   = (const float*)d_in[3];
    const float* outdeg = (const float*)d_in[4];
    const float* indeg  = (const float*)d_in[5];
    const float* hopatt = (const float*)d_in[6];
    const float* thout  = (const float*)d_in[7];
    const float* thin   = (const float*)d_in[8];
    const float* Theta  = (const float*)d_in[9];
    float* out = (float*)d_out;

    int nNodes = in_sizes[0] / DFEAT;
    int nEdges = in_sizes[1];

    char* ws = (char*)d_ws;
    size_t off = 0;
    auto alloc = [&](size_t bytes) {
        void* p = ws + off;
        off += (bytes + 255) & ~(size_t)255;
        return p;
    };
    size_t xBytes = (size_t)nNodes * DFEAT * sizeof(unsigned short);
    unsigned short* XAout = (unsigned short*)alloc(xBytes);
    unsigned short* XAin  = (unsigned short*)alloc(xBytes);
    unsigned short* XBout = (unsigned short*)alloc(xBytes);
    unsigned short* XBin  = (unsigned short*)alloc(xBytes);
    int*   rowptr = (int*)alloc((size_t)(nNodes + 1) * sizeof(int));
    int*   colptr = (int*)alloc((size_t)(nNodes + 1) * sizeof(int));
    int*   curR   = (int*)alloc((size_t)nNodes * sizeof(int));
    int*   curC   = (int*)alloc((size_t)nNodes * sizeof(int));
    int2*  pairsR = (int2*)alloc((size_t)nEdges * sizeof(int2));
    int2*  pairsC = (int2*)alloc((size_t)nEdges * sizeof(int2));
    int nChunks = (nNodes + 1023) / 1024;
    int*   bsum  = (int*)alloc((size_t)(2 * nChunks) * sizeof(int));
    float* coefs = (float*)alloc(8 * sizeof(float));

    int n4 = nNodes * (DFEAT / 4);
    int eBlocks = (nEdges + 255) / 256;
    int ihBlocks = ((n4 > nEdges ? n4 : nEdges) + 255) / 256;
    int nodeBlocks = (nNodes + 3) / 4;       // 4 waves per 256-thread block

    // ---- build phase ----
    hipMemsetAsync(rowptr, 0, (size_t)(nNodes + 1) * sizeof(int), stream);
    hipMemsetAsync(colptr, 0, (size_t)(nNodes + 1) * sizeof(int), stream);
    init_hist<<<ihBlocks, 256, 0, stream>>>(H, outdeg, indeg, hopatt, thout, thin,
                                            erow, ecol, XAout, XAin,
                                            rowptr, colptr, coefs, n4, nEdges);
    scan_reduce<<<2 * nChunks, 256, 0, stream>>>(rowptr, colptr, bsum, nNodes, nChunks);
    scan_spine<<<2, 64, 0, stream>>>(bsum, nChunks);
    scan_down<<<2 * nChunks, 256, 0, stream>>>(rowptr, curR, colptr, curC, bsum,
                                               nNodes, nChunks, nEdges);
    scatter_kernel<<<eBlocks, 256, 0, stream>>>(erow, ecol, eval, curR, curC,
                                                pairsR, pairsC, nEdges);

    // ---- hop phase (sum accumulates in d_out; LAST fuses epilogue) ----
    spmm_fused<1, 0><<<nodeBlocks, 256, 0, stream>>>(rowptr, pairsR, colptr, pairsC,
                                                     XAout, XAin, XBout, XBin,
                                                     out, nullptr, nullptr, coefs,
                                                     0, nNodes);
    spmm_fused<0, 0><<<nodeBlocks, 256, 0, stream>>>(rowptr, pairsR, colptr, pairsC,
                                                     XBout, XBin, XAout, XAin,
                                                     out, nullptr, nullptr, coefs,
                                                     1, nNodes);
    spmm_fused<0, 1><<<nodeBlocks, 256, 0, stream>>>(rowptr, pairsR, colptr, pairsC,
                                                     XAout, XAin, nullptr, nullptr,
                                                     out, H, Theta, coefs,
                                                     2, nNodes);
}

// Round 5
// 497.774 us; speedup vs baseline: 16.4563x; 1.6580x over previous
//
#include <hip/hip_runtime.h>

#define DFEAT 64
#define BKT_SHIFT 8            // 256 nodes per bucket
#define BKT_NODES 256
#define NBMAX 512              // supports up to 131072 nodes
#define CH 4096                // edges per partition chunk
#define SRC_BITS 18            // src index bits in packed record
#define SRC_MASK ((1 << SRC_BITS) - 1)

__device__ __forceinline__ unsigned short f2bf(float f) {
    unsigned u = __float_as_uint(f);
    u += 0x7FFFu + ((u >> 16) & 1u);        // round-to-nearest-even
    return (unsigned short)(u >> 16);
}
__device__ __forceinline__ float bf2f(unsigned short h) {
    return __uint_as_float((unsigned)h << 16);
}

// ---------------------------------------------------------------------------
// init: X_out = bf16(max(outdeg,1e-8)*H) ; X_in = bf16(max(indeg,1e-8)*H);
// thread 0 computes softmax(hop_att)*theta coefs. (No histogram here.)
// ---------------------------------------------------------------------------
__global__ void init_kernel(const float* __restrict__ H,
                            const float* __restrict__ outdeg,
                            const float* __restrict__ indeg,
                            const float* __restrict__ hop_att,
                            const float* __restrict__ th_out,
                            const float* __restrict__ th_in,
                            unsigned short* __restrict__ XAout,
                            unsigned short* __restrict__ XAin,
                            float* __restrict__ coefs, int n4) {
    int idx = blockIdx.x * blockDim.x + threadIdx.x;
    if (idx == 0) {
        float m = fmaxf(fmaxf(hop_att[0], hop_att[1]), hop_att[2]);
        float e0 = __expf(hop_att[0] - m);
        float e1 = __expf(hop_att[1] - m);
        float e2 = __expf(hop_att[2] - m);
        float inv = 1.0f / (e0 + e1 + e2);
        coefs[0] = e0 * inv * th_out[0]; coefs[1] = e0 * inv * th_in[0];
        coefs[2] = e1 * inv * th_out[1]; coefs[3] = e1 * inv * th_in[1];
        coefs[4] = e2 * inv * th_out[2]; coefs[5] = e2 * inv * th_in[2];
    }
    if (idx >= n4) return;
    int row = idx >> 4;                       // 16 float4 per 64-wide row
    float4 h = reinterpret_cast<const float4*>(H)[idx];
    float doo = fmaxf(outdeg[row], 1e-8f);
    float dii = fmaxf(indeg[row], 1e-8f);
    reinterpret_cast<ushort4*>(XAout)[idx] =
        make_ushort4(f2bf(h.x * doo), f2bf(h.y * doo), f2bf(h.z * doo), f2bf(h.w * doo));
    reinterpret_cast<ushort4*>(XAin)[idx] =
        make_ushort4(f2bf(h.x * dii), f2bf(h.y * dii), f2bf(h.z * dii), f2bf(h.w * dii));
}

// ---------------------------------------------------------------------------
// hist2d: per-chunk LDS histogram over buckets, both directions.
// cnt2 layout: idx(dir,b,k) = (dir*nB + b)*nBlkA + k. No global atomics.
// ---------------------------------------------------------------------------
__global__ __launch_bounds__(256) void hist2d_kernel(
        const int* __restrict__ erow, const int* __restrict__ ecol,
        int* __restrict__ cnt2, int nEdges, int nB, int nBlkA) {
    __shared__ int hR[NBMAX], hC[NBMAX];
    int k = blockIdx.x;
    for (int i = threadIdx.x; i < nB; i += 256) { hR[i] = 0; hC[i] = 0; }
    __syncthreads();
    int base = k * CH;
    int nV = min(CH, nEdges - base);
    for (int i = threadIdx.x; i < nV; i += 256) {
        atomicAdd(&hR[erow[base + i] >> BKT_SHIFT], 1);
        atomicAdd(&hC[ecol[base + i] >> BKT_SHIFT], 1);
    }
    __syncthreads();
    for (int b = threadIdx.x; b < nB; b += 256) {
        cnt2[(size_t)b * nBlkA + k] = hR[b];
        cnt2[((size_t)nB + b) * nBlkA + k] = hC[b];
    }
}

// ---------------------------------------------------------------------------
// generic hierarchical exclusive scan (single array, in place)
// ---------------------------------------------------------------------------
__global__ void scan_reduce1(const int* __restrict__ p, int* __restrict__ bsum,
                             int n) {
    int t = threadIdx.x, lane = t & 63, wid = t >> 6;
    int base = blockIdx.x * 1024 + t * 4;
    int s = 0;
#pragma unroll
    for (int i = 0; i < 4; ++i) { int idx = base + i; if (idx < n) s += p[idx]; }
#pragma unroll
    for (int o = 32; o >= 1; o >>= 1) s += __shfl_down(s, o, 64);
    __shared__ int wsum[4];
    if (lane == 0) wsum[wid] = s;
    __syncthreads();
    if (t == 0) bsum[blockIdx.x] = wsum[0] + wsum[1] + wsum[2] + wsum[3];
}

__global__ void scan_spine1(int* __restrict__ bsum, int nChunks) {
    int lane = threadIdx.x;                    // single 64-lane wave
    int carry = 0;
    for (int base = 0; base < nChunks; base += 64) {
        int i = base + lane;
        int v = (i < nChunks) ? bsum[i] : 0;
        int s = v;
#pragma unroll
        for (int o = 1; o < 64; o <<= 1) {
            int x = __shfl_up(s, o, 64);
            if (lane >= o) s += x;
        }
        if (i < nChunks) bsum[i] = carry + s - v;
        carry += __shfl(s, 63, 64);
    }
}

__global__ void scan_down1(int* __restrict__ p, const int* __restrict__ bsum,
                           int n) {
    int t = threadIdx.x, lane = t & 63, wid = t >> 6;
    int base = blockIdx.x * 1024 + t * 4;
    int v[4];
    int tsum = 0;
#pragma unroll
    for (int i = 0; i < 4; ++i) {
        v[i] = (base + i < n) ? p[base + i] : 0;
        tsum += v[i];
    }
    int inc = tsum;
#pragma unroll
    for (int o = 1; o < 64; o <<= 1) {
        int x = __shfl_up(inc, o, 64);
        if (lane >= o) inc += x;
    }
    __shared__ int wsum[4];
    if (lane == 63) wsum[wid] = inc;
    __syncthreads();
    int woff = 0;
    for (int w = 0; w < wid; ++w) woff += wsum[w];
    int run = bsum[blockIdx.x] + woff + inc - tsum;
#pragma unroll
    for (int i = 0; i < 4; ++i) {
        if (base + i < n) p[base + i] = run;
        run += v[i];
    }
}

// ---------------------------------------------------------------------------
// partA: LDS-staged radix partition of edges into 256-node buckets.
// Record: x = src | (dstLocal << SRC_BITS), y = f32 val bits. Copy-out is
// bucket-grouped -> full-line global writes (no 8x amplification).
// grid = (nBlkA, 2): blockIdx.y = direction (0: by row, 1: by col).
// ---------------------------------------------------------------------------
__global__ __launch_bounds__(256) void partA_kernel(
        const int* __restrict__ erow, const int* __restrict__ ecol,
        const float* __restrict__ eval, const int* __restrict__ base2,
        int2* __restrict__ recR, int2* __restrict__ recC,
        int nEdges, int nB, int nBlkA) {
    __shared__ int hist[NBMAX], scn[NBMAX], cur[NBMAX], gbase[NBMAX];
    __shared__ unsigned short keybuf[CH], slotKey[CH];
    __shared__ int2 stage[CH];
    int dir = blockIdx.y;
    const int* dk = dir ? ecol : erow;      // dst side (grouping key)
    const int* ds = dir ? erow : ecol;      // src side (payload)
    int2* rec = dir ? recC : recR;
    int k = blockIdx.x;
    int base = k * CH;
    int nV = min(CH, nEdges - base);
    for (int i = threadIdx.x; i < nB; i += 256) {
        hist[i] = 0; cur[i] = 0;
        gbase[i] = base2[((size_t)dir * nB + i) * nBlkA + k] - dir * nEdges;
    }
    __syncthreads();
    for (int i = threadIdx.x; i < nV; i += 256) {
        int key = dk[base + i] >> BKT_SHIFT;
        keybuf[i] = (unsigned short)key;
        atomicAdd(&hist[key], 1);
    }
    __syncthreads();
    if (threadIdx.x < 64) {                 // wave-0 exclusive scan hist->scn
        int lane = threadIdx.x;
        int carry = 0;
        for (int bb = 0; bb < nB; bb += 64) {
            int i = bb + lane;
            int v = (i < nB) ? hist[i] : 0;
            int s = v;
#pragma unroll
            for (int o = 1; o < 64; o <<= 1) {
                int x = __shfl_up(s, o, 64);
                if (lane >= o) s += x;
            }
            if (i < nB) scn[i] = carry + s - v;
            carry += __shfl(s, 63, 64);
        }
    }
    __syncthreads();
    for (int i = threadIdx.x; i < nV; i += 256) {   // compact into LDS
        int e = base + i;
        int key = keybuf[i];
        int slot = scn[key] + atomicAdd(&cur[key], 1);
        int dl = dk[e] & (BKT_NODES - 1);
        stage[slot] = make_int2(ds[e] | (dl << SRC_BITS), __float_as_int(eval[e]));
        slotKey[slot] = (unsigned short)key;
    }
    __syncthreads();
    for (int i = threadIdx.x; i < nV; i += 256) {   // grouped copy-out
        int key = slotKey[i];
        rec[gbase[key] + (i - scn[key])] = stage[i];
    }
}

// ---------------------------------------------------------------------------
// partB: per-bucket exact scatter. Derives per-node layout (hist+scan of 256
// dstLocal) in LDS, emits rowptr/colptr from the scan, writes CSR/CSC pairs
// into the bucket's own ~32KB window (L2-resident -> coalesced eviction).
// grid = (nB, 2).
// ---------------------------------------------------------------------------
__global__ __launch_bounds__(256) void partB_kernel(
        const int2* __restrict__ recR, const int2* __restrict__ recC,
        const int* __restrict__ base2,
        int* __restrict__ rowptr, int* __restrict__ colptr,
        int2* __restrict__ pairsR, int2* __restrict__ pairsC,
        int nEdges, int nB, int nBlkA, int nNodes) {
    __shared__ int hist[BKT_NODES], scn[BKT_NODES], cur[BKT_NODES];
    int dir = blockIdx.y;
    int b = blockIdx.x;
    const int2* rec = dir ? recC : recR;
    int2* pairs = dir ? pairsC : pairsR;
    int* nptr = dir ? colptr : rowptr;
    int segB = base2[((size_t)dir * nB + b) * nBlkA] - dir * nEdges;
    int segE = (b == nB - 1) ? nEdges
             : base2[((size_t)dir * nB + b + 1) * nBlkA] - dir * nEdges;
    int t = threadIdx.x;
    hist[t] = 0; cur[t] = 0;
    __syncthreads();
    for (int j = segB + t; j < segE; j += 256)
        atomicAdd(&hist[(rec[j].x >> SRC_BITS) & (BKT_NODES - 1)], 1);
    __syncthreads();
    if (t < 64) {                           // wave-0 exclusive scan (256)
        int lane = t, carry = 0;
        for (int bb = 0; bb < BKT_NODES; bb += 64) {
            int i = bb + lane;
            int v = hist[i], s = v;
#pragma unroll
            for (int o = 1; o < 64; o <<= 1) {
                int x = __shfl_up(s, o, 64);
                if (lane >= o) s += x;
            }
            scn[i] = carry + s - v;
            carry += __shfl(s, 63, 64);
        }
    }
    __syncthreads();
    int node = (b << BKT_SHIFT) + t;
    if (node < nNodes) nptr[node] = segB + scn[t];
    if (b == nB - 1 && t == 0) nptr[nNodes] = nEdges;
    for (int j = segB + t; j < segE; j += 256) {
        int2 r = rec[j];
        int dl = (r.x >> SRC_BITS) & (BKT_NODES - 1);
        int slot = segB + scn[dl] + atomicAdd(&cur[dl], 1);
        pairs[slot] = make_int2(r.x & SRC_MASK, r.y);
    }
}

// ---------------------------------------------------------------------------
// fused spmm, both directions + hop accumulation. One 64-lane wave per node,
// lane = feature dim. X/Y bf16, sum f32. 4x unrolled gather for MLP.
// LAST variant fuses sigmoid(sum @ Theta) + H epilogue.
// ---------------------------------------------------------------------------
template <int FIRST, int LAST>
__global__ __launch_bounds__(256) void spmm_fused(
        const int* __restrict__ rowptr, const int2* __restrict__ pairsR,
        const int* __restrict__ colptr, const int2* __restrict__ pairsC,
        const unsigned short* __restrict__ Xout,
        const unsigned short* __restrict__ Xin,
        unsigned short* __restrict__ Yout, unsigned short* __restrict__ Yin,
        float* __restrict__ sum,
        const float* __restrict__ H, const float* __restrict__ Theta,
        const float* __restrict__ coefs,
        int k, int nNodes) {
    __shared__ float Th[LAST ? 64 * 64 : 1];
    __shared__ float Srow[LAST ? 4 * 64 : 1];
    int wid = threadIdx.x >> 6;
    int lane = threadIdx.x & 63;
    int node = blockIdx.x * 4 + wid;
    bool live = node < nNodes;
    if (!LAST && !live) return;
    int nodeC = live ? node : 0;

    if (LAST) {
        for (int i = threadIdx.x; i < 64 * 64; i += 256) Th[i] = Theta[i];
    }

    float co = coefs[2 * k], ci = coefs[2 * k + 1];
    float a0 = 0.f, a1 = 0.f, a2 = 0.f, a3 = 0.f;
    int b = rowptr[nodeC], e = rowptr[nodeC + 1];
    int j = b;
    for (; j + 4 <= e; j += 4) {
        int2 p0 = pairsR[j];
        int2 p1 = pairsR[j + 1];
        int2 p2 = pairsR[j + 2];
        int2 p3 = pairsR[j + 3];
        float x0 = bf2f(Xout[p0.x * DFEAT + lane]);
        float x1 = bf2f(Xout[p1.x * DFEAT + lane]);
        float x2 = bf2f(Xout[p2.x * DFEAT + lane]);
        float x3 = bf2f(Xout[p3.x * DFEAT + lane]);
        a0 += __int_as_float(p0.y) * x0;
        a1 += __int_as_float(p1.y) * x1;
        a2 += __int_as_float(p2.y) * x2;
        a3 += __int_as_float(p3.y) * x3;
    }
    for (; j < e; ++j) {
        int2 p = pairsR[j];
        a0 += __int_as_float(p.y) * bf2f(Xout[p.x * DFEAT + lane]);
    }
    float accO = (a0 + a1) + (a2 + a3);

    a0 = a1 = a2 = a3 = 0.f;
    b = colptr[nodeC]; e = colptr[nodeC + 1];
    j = b;
    for (; j + 4 <= e; j += 4) {
        int2 p0 = pairsC[j];
        int2 p1 = pairsC[j + 1];
        int2 p2 = pairsC[j + 2];
        int2 p3 = pairsC[j + 3];
        float x0 = bf2f(Xin[p0.x * DFEAT + lane]);
        float x1 = bf2f(Xin[p1.x * DFEAT + lane]);
        float x2 = bf2f(Xin[p2.x * DFEAT + lane]);
        float x3 = bf2f(Xin[p3.x * DFEAT + lane]);
        a0 += __int_as_float(p0.y) * x0;
        a1 += __int_as_float(p1.y) * x1;
        a2 += __int_as_float(p2.y) * x2;
        a3 += __int_as_float(p3.y) * x3;
    }
    for (; j < e; ++j) {
        int2 p = pairsC[j];
        a0 += __int_as_float(p.y) * bf2f(Xin[p.x * DFEAT + lane]);
    }
    float accI = (a0 + a1) + (a2 + a3);

    int off = nodeC * DFEAT + lane;
    if (!LAST) {
        Yout[off] = f2bf(accO);
        Yin[off] = f2bf(accI);
        float s = co * accO + ci * accI;
        if (FIRST) sum[off] = s;
        else       sum[off] += s;
    } else {
        float s = sum[off] + co * accO + ci * accI;
        __syncthreads();
        Srow[wid * 64 + lane] = s;
        float acc = 0.f;
#pragma unroll
        for (int kk = 0; kk < 64; ++kk)
            acc += Srow[wid * 64 + kk] * Th[kk * 64 + lane];
        if (live)
            sum[off] = 1.0f / (1.0f + __expf(-acc)) + H[off];
    }
}

extern "C" void kernel_launch(void* const* d_in, const int* in_sizes, int n_in,
                              void* d_out, int out_size, void* d_ws, size_t ws_size,
                              hipStream_t stream) {
    const float* H      = (const float*)d_in[0];
    const int*   erow   = (const int*)d_in[1];
    const int*   ecol   = (const int*)d_in[2];
    const float* eval   = (const float*)d_in[3];
    const float* outdeg = (const float*)d_in[4];
    const float* indeg  = (const float*)d_in[5];
    const float* hopatt = (const float*)d_in[6];
    const float* thout  = (const float*)d_in[7];
    const float* thin   = (const float*)d_in[8];
    const float* Theta  = (const float*)d_in[9];
    float* out = (float*)d_out;

    int nNodes = in_sizes[0] / DFEAT;
    int nEdges = in_sizes[1];

    char* ws = (char*)d_ws;
    size_t off = 0;
    auto alloc = [&](size_t bytes) {
        void* p = ws + off;
        off += (bytes + 255) & ~(size_t)255;
        return p;
    };
    size_t xBytes = (size_t)nNodes * DFEAT * sizeof(unsigned short);
    unsigned short* XAout = (unsigned short*)alloc(xBytes);
    unsigned short* XAin  = (unsigned short*)alloc(xBytes);
    unsigned short* XBout = (unsigned short*)alloc(xBytes);
    unsigned short* XBin  = (unsigned short*)alloc(xBytes);
    int*   rowptr = (int*)alloc((size_t)(nNodes + 1) * sizeof(int));
    int*   colptr = (int*)alloc((size_t)(nNodes + 1) * sizeof(int));
    int2*  recR   = (int2*)alloc((size_t)nEdges * sizeof(int2));
    int2*  recC   = (int2*)alloc((size_t)nEdges * sizeof(int2));
    int2*  pairsR = (int2*)alloc((size_t)nEdges * sizeof(int2));
    int2*  pairsC = (int2*)alloc((size_t)nEdges * sizeof(int2));

    int nB    = (nNodes + BKT_NODES - 1) >> BKT_SHIFT;
    int nBlkA = (nEdges + CH - 1) / CH;
    int L = 2 * nB * nBlkA;
    int nChunks = (L + 1023) / 1024;
    int*   cnt2 = (int*)alloc((size_t)L * sizeof(int));
    int*   bsum = (int*)alloc((size_t)nChunks * sizeof(int));
    float* coefs = (float*)alloc(8 * sizeof(float));

    int n4 = nNodes * (DFEAT / 4);
    int ewBlocks = (n4 + 255) / 256;
    int nodeBlocks = (nNodes + 3) / 4;       // 4 waves per 256-thread block

    // ---- build phase ----
    init_kernel<<<ewBlocks, 256, 0, stream>>>(H, outdeg, indeg, hopatt, thout, thin,
                                              XAout, XAin, coefs, n4);
    hist2d_kernel<<<nBlkA, 256, 0, stream>>>(erow, ecol, cnt2, nEdges, nB, nBlkA);
    scan_reduce1<<<nChunks, 256, 0, stream>>>(cnt2, bsum, L);
    scan_spine1<<<1, 64, 0, stream>>>(bsum, nChunks);
    scan_down1<<<nChunks, 256, 0, stream>>>(cnt2, bsum, L);
    partA_kernel<<<dim3(nBlkA, 2), 256, 0, stream>>>(erow, ecol, eval, cnt2,
                                                     recR, recC, nEdges, nB, nBlkA);
    partB_kernel<<<dim3(nB, 2), 256, 0, stream>>>(recR, recC, cnt2,
                                                  rowptr, colptr, pairsR, pairsC,
                                                  nEdges, nB, nBlkA, nNodes);

    // ---- hop phase (sum accumulates in d_out; LAST fuses epilogue) ----
    spmm_fused<1, 0><<<nodeBlocks, 256, 0, stream>>>(rowptr, pairsR, colptr, pairsC,
                                                     XAout, XAin, XBout, XBin,
                                                     out, nullptr, nullptr, coefs,
                                                     0, nNodes);
    spmm_fused<0, 0><<<nodeBlocks, 256, 0, stream>>>(rowptr, pairsR, colptr, pairsC,
                                                     XBout, XBin, XAout, XAin,
                                                     out, nullptr, nullptr, coefs,
                                                     1, nNodes);
    spmm_fused<0, 1><<<nodeBlocks, 256, 0, stream>>>(rowptr, pairsR, colptr, pairsC,
                                                     XAout, XAin, nullptr, nullptr,
                                                     out, H, Theta, coefs,
                                                     2, nNodes);
}

// Round 6
// 431.183 us; speedup vs baseline: 18.9977x; 1.1544x over previous
//
#include <hip/hip_runtime.h>
#include <hip/hip_fp16.h>

#define DFEAT 64
#define BKT_SHIFT 8            // 256 nodes per bucket
#define BKT_NODES 256
#define NBMAX 512              // supports up to 131072 nodes
#define CH 4096                // edges per partition chunk
#define SRC_BITS 18            // src index bits in packed record
#define SRC_MASK ((1 << SRC_BITS) - 1)

__device__ __forceinline__ unsigned short f2h(float f) {
    return __half_as_ushort(__float2half(f));
}
__device__ __forceinline__ float h2f(unsigned short u) {
    return __half2float(__ushort_as_half(u));
}

// ---------------------------------------------------------------------------
// init: X_out = f16(max(outdeg,1e-8)*H) ; X_in = f16(max(indeg,1e-8)*H);
// thread 0 computes softmax(hop_att)*theta coefs.
// ---------------------------------------------------------------------------
__global__ void init_kernel(const float* __restrict__ H,
                            const float* __restrict__ outdeg,
                            const float* __restrict__ indeg,
                            const float* __restrict__ hop_att,
                            const float* __restrict__ th_out,
                            const float* __restrict__ th_in,
                            unsigned short* __restrict__ XAout,
                            unsigned short* __restrict__ XAin,
                            float* __restrict__ coefs, int n4) {
    int idx = blockIdx.x * blockDim.x + threadIdx.x;
    if (idx == 0) {
        float m = fmaxf(fmaxf(hop_att[0], hop_att[1]), hop_att[2]);
        float e0 = __expf(hop_att[0] - m);
        float e1 = __expf(hop_att[1] - m);
        float e2 = __expf(hop_att[2] - m);
        float inv = 1.0f / (e0 + e1 + e2);
        coefs[0] = e0 * inv * th_out[0]; coefs[1] = e0 * inv * th_in[0];
        coefs[2] = e1 * inv * th_out[1]; coefs[3] = e1 * inv * th_in[1];
        coefs[4] = e2 * inv * th_out[2]; coefs[5] = e2 * inv * th_in[2];
    }
    if (idx >= n4) return;
    int row = idx >> 4;                       // 16 float4 per 64-wide row
    float4 h = reinterpret_cast<const float4*>(H)[idx];
    float doo = fmaxf(outdeg[row], 1e-8f);
    float dii = fmaxf(indeg[row], 1e-8f);
    reinterpret_cast<ushort4*>(XAout)[idx] =
        make_ushort4(f2h(h.x * doo), f2h(h.y * doo), f2h(h.z * doo), f2h(h.w * doo));
    reinterpret_cast<ushort4*>(XAin)[idx] =
        make_ushort4(f2h(h.x * dii), f2h(h.y * dii), f2h(h.z * dii), f2h(h.w * dii));
}

// ---------------------------------------------------------------------------
// hist2d: per-chunk LDS histogram over buckets, both directions.
// cnt2 layout: idx(dir,b,k) = (dir*nB + b)*nBlkA + k. No global atomics.
// ---------------------------------------------------------------------------
__global__ __launch_bounds__(256) void hist2d_kernel(
        const int* __restrict__ erow, const int* __restrict__ ecol,
        int* __restrict__ cnt2, int nEdges, int nB, int nBlkA) {
    __shared__ int hR[NBMAX], hC[NBMAX];
    int k = blockIdx.x;
    for (int i = threadIdx.x; i < nB; i += 256) { hR[i] = 0; hC[i] = 0; }
    __syncthreads();
    int base = k * CH;
    int nV = min(CH, nEdges - base);
    for (int i = threadIdx.x; i < nV; i += 256) {
        atomicAdd(&hR[erow[base + i] >> BKT_SHIFT], 1);
        atomicAdd(&hC[ecol[base + i] >> BKT_SHIFT], 1);
    }
    __syncthreads();
    for (int b = threadIdx.x; b < nB; b += 256) {
        cnt2[(size_t)b * nBlkA + k] = hR[b];
        cnt2[((size_t)nB + b) * nBlkA + k] = hC[b];
    }
}

// ---------------------------------------------------------------------------
// generic hierarchical exclusive scan (single array, in place)
// ---------------------------------------------------------------------------
__global__ void scan_reduce1(const int* __restrict__ p, int* __restrict__ bsum,
                             int n) {
    int t = threadIdx.x, lane = t & 63, wid = t >> 6;
    int base = blockIdx.x * 1024 + t * 4;
    int s = 0;
#pragma unroll
    for (int i = 0; i < 4; ++i) { int idx = base + i; if (idx < n) s += p[idx]; }
#pragma unroll
    for (int o = 32; o >= 1; o >>= 1) s += __shfl_down(s, o, 64);
    __shared__ int wsum[4];
    if (lane == 0) wsum[wid] = s;
    __syncthreads();
    if (t == 0) bsum[blockIdx.x] = wsum[0] + wsum[1] + wsum[2] + wsum[3];
}

__global__ void scan_spine1(int* __restrict__ bsum, int nChunks) {
    int lane = threadIdx.x;                    // single 64-lane wave
    int carry = 0;
    for (int base = 0; base < nChunks; base += 64) {
        int i = base + lane;
        int v = (i < nChunks) ? bsum[i] : 0;
        int s = v;
#pragma unroll
        for (int o = 1; o < 64; o <<= 1) {
            int x = __shfl_up(s, o, 64);
            if (lane >= o) s += x;
        }
        if (i < nChunks) bsum[i] = carry + s - v;
        carry += __shfl(s, 63, 64);
    }
}

__global__ void scan_down1(int* __restrict__ p, const int* __restrict__ bsum,
                           int n) {
    int t = threadIdx.x, lane = t & 63, wid = t >> 6;
    int base = blockIdx.x * 1024 + t * 4;
    int v[4];
    int tsum = 0;
#pragma unroll
    for (int i = 0; i < 4; ++i) {
        v[i] = (base + i < n) ? p[base + i] : 0;
        tsum += v[i];
    }
    int inc = tsum;
#pragma unroll
    for (int o = 1; o < 64; o <<= 1) {
        int x = __shfl_up(inc, o, 64);
        if (lane >= o) inc += x;
    }
    __shared__ int wsum[4];
    if (lane == 63) wsum[wid] = inc;
    __syncthreads();
    int woff = 0;
    for (int w = 0; w < wid; ++w) woff += wsum[w];
    int run = bsum[blockIdx.x] + woff + inc - tsum;
#pragma unroll
    for (int i = 0; i < 4; ++i) {
        if (base + i < n) p[base + i] = run;
        run += v[i];
    }
}

// ---------------------------------------------------------------------------
// partA: LDS-staged radix partition of edges into 256-node buckets.
// Record: x = src | (dstLocal << SRC_BITS), y = f32 val bits. Copy-out is
// bucket-grouped -> full-line global writes (no 8x amplification).
// grid = (nBlkA, 2): blockIdx.y = direction (0: by row, 1: by col).
// ---------------------------------------------------------------------------
__global__ __launch_bounds__(256) void partA_kernel(
        const int* __restrict__ erow, const int* __restrict__ ecol,
        const float* __restrict__ eval, const int* __restrict__ base2,
        int2* __restrict__ recR, int2* __restrict__ recC,
        int nEdges, int nB, int nBlkA) {
    __shared__ int hist[NBMAX], scn[NBMAX], cur[NBMAX], gbase[NBMAX];
    __shared__ unsigned short keybuf[CH], slotKey[CH];
    __shared__ int2 stage[CH];
    int dir = blockIdx.y;
    const int* dk = dir ? ecol : erow;      // dst side (grouping key)
    const int* ds = dir ? erow : ecol;      // src side (payload)
    int2* rec = dir ? recC : recR;
    int k = blockIdx.x;
    int base = k * CH;
    int nV = min(CH, nEdges - base);
    for (int i = threadIdx.x; i < nB; i += 256) {
        hist[i] = 0; cur[i] = 0;
        gbase[i] = base2[((size_t)dir * nB + i) * nBlkA + k] - dir * nEdges;
    }
    __syncthreads();
    for (int i = threadIdx.x; i < nV; i += 256) {
        int key = dk[base + i] >> BKT_SHIFT;
        keybuf[i] = (unsigned short)key;
        atomicAdd(&hist[key], 1);
    }
    __syncthreads();
    if (threadIdx.x < 64) {                 // wave-0 exclusive scan hist->scn
        int lane = threadIdx.x;
        int carry = 0;
        for (int bb = 0; bb < nB; bb += 64) {
            int i = bb + lane;
            int v = (i < nB) ? hist[i] : 0;
            int s = v;
#pragma unroll
            for (int o = 1; o < 64; o <<= 1) {
                int x = __shfl_up(s, o, 64);
                if (lane >= o) s += x;
            }
            if (i < nB) scn[i] = carry + s - v;
            carry += __shfl(s, 63, 64);
        }
    }
    __syncthreads();
    for (int i = threadIdx.x; i < nV; i += 256) {   // compact into LDS
        int e = base + i;
        int key = keybuf[i];
        int slot = scn[key] + atomicAdd(&cur[key], 1);
        int dl = dk[e] & (BKT_NODES - 1);
        stage[slot] = make_int2(ds[e] | (dl << SRC_BITS), __float_as_int(eval[e]));
        slotKey[slot] = (unsigned short)key;
    }
    __syncthreads();
    for (int i = threadIdx.x; i < nV; i += 256) {   // grouped copy-out
        int key = slotKey[i];
        rec[gbase[key] + (i - scn[key])] = stage[i];
    }
}

// ---------------------------------------------------------------------------
// partB: per-bucket exact scatter. Derives per-node layout (hist+scan of 256
// dstLocal) in LDS, emits rowptr/colptr from the scan, writes packed pairs
// (src 17b | f16-val-sans-sign 15b) into the bucket's own window.
// grid = (nB, 2).
// ---------------------------------------------------------------------------
__global__ __launch_bounds__(256) void partB_kernel(
        const int2* __restrict__ recR, const int2* __restrict__ recC,
        const int* __restrict__ base2,
        int* __restrict__ rowptr, int* __restrict__ colptr,
        unsigned* __restrict__ pairsR, unsigned* __restrict__ pairsC,
        int nEdges, int nB, int nBlkA, int nNodes) {
    __shared__ int hist[BKT_NODES], scn[BKT_NODES], cur[BKT_NODES];
    int dir = blockIdx.y;
    int b = blockIdx.x;
    const int2* rec = dir ? recC : recR;
    unsigned* pairs = dir ? pairsC : pairsR;
    int* nptr = dir ? colptr : rowptr;
    int segB = base2[((size_t)dir * nB + b) * nBlkA] - dir * nEdges;
    int segE = (b == nB - 1) ? nEdges
             : base2[((size_t)dir * nB + b + 1) * nBlkA] - dir * nEdges;
    int t = threadIdx.x;
    hist[t] = 0; cur[t] = 0;
    __syncthreads();
    for (int j = segB + t; j < segE; j += 256)
        atomicAdd(&hist[(rec[j].x >> SRC_BITS) & (BKT_NODES - 1)], 1);
    __syncthreads();
    if (t < 64) {                           // wave-0 exclusive scan (256)
        int lane = t, carry = 0;
        for (int bb = 0; bb < BKT_NODES; bb += 64) {
            int i = bb + lane;
            int v = hist[i], s = v;
#pragma unroll
            for (int o = 1; o < 64; o <<= 1) {
                int x = __shfl_up(s, o, 64);
                if (lane >= o) s += x;
            }
            scn[i] = carry + s - v;
            carry += __shfl(s, 63, 64);
        }
    }
    __syncthreads();
    int node = (b << BKT_SHIFT) + t;
    if (node < nNodes) nptr[node] = segB + scn[t];
    if (b == nB - 1 && t == 0) nptr[nNodes] = nEdges;
    for (int j = segB + t; j < segE; j += 256) {
        int2 r = rec[j];
        int dl = (r.x >> SRC_BITS) & (BKT_NODES - 1);
        int slot = segB + scn[dl] + atomicAdd(&cur[dl], 1);
        unsigned vh = f2h(__int_as_float(r.y)) & 0x7FFFu;   // val>=0: sign bit 0
        pairs[slot] = ((unsigned)(r.x & SRC_MASK) << 15) | vh;
    }
}

// ---------------------------------------------------------------------------
// fused spmm, both directions + hop accumulation. One 64-lane wave per node,
// lane = feature dim. X/Y f16, sum f16, packed 4B pairs. 8/4/1 unrolled
// gathers. LAST fuses sigmoid(sum @ Theta) + H epilogue, writes f32 out.
// ---------------------------------------------------------------------------
template <int FIRST, int LAST>
__global__ __launch_bounds__(256) void spmm_fused(
        const int* __restrict__ rowptr, const unsigned* __restrict__ pairsR,
        const int* __restrict__ colptr, const unsigned* __restrict__ pairsC,
        const __half* __restrict__ Xout, const __half* __restrict__ Xin,
        unsigned short* __restrict__ Yout, unsigned short* __restrict__ Yin,
        unsigned short* __restrict__ sumH, float* __restrict__ out,
        const float* __restrict__ H, const float* __restrict__ Theta,
        const float* __restrict__ coefs,
        int k, int nNodes) {
    __shared__ float Th[LAST ? 64 * 64 : 1];
    __shared__ float Srow[LAST ? 4 * 64 : 1];
    int wid = threadIdx.x >> 6;
    int lane = threadIdx.x & 63;
    int node = blockIdx.x * 4 + wid;
    bool live = node < nNodes;
    if (!LAST && !live) return;
    int nodeC = live ? node : 0;

    if (LAST) {
        for (int i = threadIdx.x; i < 64 * 64; i += 256) Th[i] = Theta[i];
    }

    float co = coefs[2 * k], ci = coefs[2 * k + 1];

    float accO, accI;
#pragma unroll
    for (int dir = 0; dir < 2; ++dir) {
        const unsigned* pairs = dir ? pairsC : pairsR;
        const __half* X = dir ? Xin : Xout;
        const int* ptr = dir ? colptr : rowptr;
        float a0 = 0.f, a1 = 0.f, a2 = 0.f, a3 = 0.f;
        float a4 = 0.f, a5 = 0.f, a6 = 0.f, a7 = 0.f;
        int b = ptr[nodeC], e = ptr[nodeC + 1];
        int j = b;
        for (; j + 8 <= e; j += 8) {
            unsigned p0 = pairs[j],     p1 = pairs[j + 1];
            unsigned p2 = pairs[j + 2], p3 = pairs[j + 3];
            unsigned p4 = pairs[j + 4], p5 = pairs[j + 5];
            unsigned p6 = pairs[j + 6], p7 = pairs[j + 7];
            float x0 = __half2float(X[(p0 >> 15) * DFEAT + lane]);
            float x1 = __half2float(X[(p1 >> 15) * DFEAT + lane]);
            float x2 = __half2float(X[(p2 >> 15) * DFEAT + lane]);
            float x3 = __half2float(X[(p3 >> 15) * DFEAT + lane]);
            float x4 = __half2float(X[(p4 >> 15) * DFEAT + lane]);
            float x5 = __half2float(X[(p5 >> 15) * DFEAT + lane]);
            float x6 = __half2float(X[(p6 >> 15) * DFEAT + lane]);
            float x7 = __half2float(X[(p7 >> 15) * DFEAT + lane]);
            a0 += h2f(p0 & 0x7FFFu) * x0;
            a1 += h2f(p1 & 0x7FFFu) * x1;
            a2 += h2f(p2 & 0x7FFFu) * x2;
            a3 += h2f(p3 & 0x7FFFu) * x3;
            a4 += h2f(p4 & 0x7FFFu) * x4;
            a5 += h2f(p5 & 0x7FFFu) * x5;
            a6 += h2f(p6 & 0x7FFFu) * x6;
            a7 += h2f(p7 & 0x7FFFu) * x7;
        }
        for (; j + 4 <= e; j += 4) {
            unsigned p0 = pairs[j],     p1 = pairs[j + 1];
            unsigned p2 = pairs[j + 2], p3 = pairs[j + 3];
            float x0 = __half2float(X[(p0 >> 15) * DFEAT + lane]);
            float x1 = __half2float(X[(p1 >> 15) * DFEAT + lane]);
            float x2 = __half2float(X[(p2 >> 15) * DFEAT + lane]);
            float x3 = __half2float(X[(p3 >> 15) * DFEAT + lane]);
            a0 += h2f(p0 & 0x7FFFu) * x0;
            a1 += h2f(p1 & 0x7FFFu) * x1;
            a2 += h2f(p2 & 0x7FFFu) * x2;
            a3 += h2f(p3 & 0x7FFFu) * x3;
        }
        for (; j < e; ++j) {
            unsigned p = pairs[j];
            a0 += h2f(p & 0x7FFFu) * __half2float(X[(p >> 15) * DFEAT + lane]);
        }
        float acc = ((a0 + a1) + (a2 + a3)) + ((a4 + a5) + (a6 + a7));
        if (dir == 0) accO = acc; else accI = acc;
    }

    int off = nodeC * DFEAT + lane;
    if (!LAST) {
        __builtin_nontemporal_store(f2h(accO), &Yout[off]);
        __builtin_nontemporal_store(f2h(accI), &Yin[off]);
        float s = co * accO + ci * accI;
        if (!FIRST) s += h2f(sumH[off]);
        __builtin_nontemporal_store(f2h(s), &sumH[off]);
    } else {
        float s = h2f(sumH[off]) + co * accO + ci * accI;
        __syncthreads();
        Srow[wid * 64 + lane] = s;
        float acc = 0.f;
#pragma unroll
        for (int kk = 0; kk < 64; ++kk)
            acc += Srow[wid * 64 + kk] * Th[kk * 64 + lane];
        if (live) {
            float r = 1.0f / (1.0f + __expf(-acc)) + H[off];
            __builtin_nontemporal_store(r, &out[off]);
        }
    }
}

extern "C" void kernel_launch(void* const* d_in, const int* in_sizes, int n_in,
                              void* d_out, int out_size, void* d_ws, size_t ws_size,
                              hipStream_t stream) {
    const float* H      = (const float*)d_in[0];
    const int*   erow   = (const int*)d_in[1];
    const int*   ecol   = (const int*)d_in[2];
    const float* eval   = (const float*)d_in[3];
    const float* outdeg = (const float*)d_in[4];
    const float* indeg  = (const float*)d_in[5];
    const float* hopatt = (const float*)d_in[6];
    const float* thout  = (const float*)d_in[7];
    const float* thin   = (const float*)d_in[8];
    const float* Theta  = (const float*)d_in[9];
    float* out = (float*)d_out;

    int nNodes = in_sizes[0] / DFEAT;
    int nEdges = in_sizes[1];

    char* ws = (char*)d_ws;
    size_t off = 0;
    auto alloc = [&](size_t bytes) {
        void* p = ws + off;
        off += (bytes + 255) & ~(size_t)255;
        return p;
    };
    size_t xBytes = (size_t)nNodes * DFEAT * sizeof(unsigned short);
    unsigned short* XAout = (unsigned short*)alloc(xBytes);
    unsigned short* XAin  = (unsigned short*)alloc(xBytes);
    unsigned short* XBout = (unsigned short*)alloc(xBytes);
    unsigned short* XBin  = (unsigned short*)alloc(xBytes);
    unsigned short* sumH  = (unsigned short*)alloc(xBytes);
    int*   rowptr = (int*)alloc((size_t)(nNodes + 1) * sizeof(int));
    int*   colptr = (int*)alloc((size_t)(nNodes + 1) * sizeof(int));
    int2*  recR   = (int2*)alloc((size_t)nEdges * sizeof(int2));
    int2*  recC   = (int2*)alloc((size_t)nEdges * sizeof(int2));
    unsigned* pairsR = (unsigned*)alloc((size_t)nEdges * sizeof(unsigned));
    unsigned* pairsC = (unsigned*)alloc((size_t)nEdges * sizeof(unsigned));

    int nB    = (nNodes + BKT_NODES - 1) >> BKT_SHIFT;
    int nBlkA = (nEdges + CH - 1) / CH;
    int L = 2 * nB * nBlkA;
    int nChunks = (L + 1023) / 1024;
    int*   cnt2 = (int*)alloc((size_t)L * sizeof(int));
    int*   bsum = (int*)alloc((size_t)nChunks * sizeof(int));
    float* coefs = (float*)alloc(8 * sizeof(float));

    int n4 = nNodes * (DFEAT / 4);
    int ewBlocks = (n4 + 255) / 256;
    int nodeBlocks = (nNodes + 3) / 4;       // 4 waves per 256-thread block

    // ---- build phase ----
    init_kernel<<<ewBlocks, 256, 0, stream>>>(H, outdeg, indeg, hopatt, thout, thin,
                                              XAout, XAin, coefs, n4);
    hist2d_kernel<<<nBlkA, 256, 0, stream>>>(erow, ecol, cnt2, nEdges, nB, nBlkA);
    scan_reduce1<<<nChunks, 256, 0, stream>>>(cnt2, bsum, L);
    scan_spine1<<<1, 64, 0, stream>>>(bsum, nChunks);
    scan_down1<<<nChunks, 256, 0, stream>>>(cnt2, bsum, L);
    partA_kernel<<<dim3(nBlkA, 2), 256, 0, stream>>>(erow, ecol, eval, cnt2,
                                                     recR, recC, nEdges, nB, nBlkA);
    partB_kernel<<<dim3(nB, 2), 256, 0, stream>>>(recR, recC, cnt2,
                                                  rowptr, colptr, pairsR, pairsC,
                                                  nEdges, nB, nBlkA, nNodes);

    // ---- hop phase (sum accumulates in f16 ws; LAST fuses epilogue) ----
    spmm_fused<1, 0><<<nodeBlocks, 256, 0, stream>>>(rowptr, pairsR, colptr, pairsC,
                                                     (const __half*)XAout, (const __half*)XAin,
                                                     XBout, XBin, sumH, nullptr,
                                                     nullptr, nullptr, coefs, 0, nNodes);
    spmm_fused<0, 0><<<nodeBlocks, 256, 0, stream>>>(rowptr, pairsR, colptr, pairsC,
                                                     (const __half*)XBout, (const __half*)XBin,
                                                     XAout, XAin, sumH, nullptr,
                                                     nullptr, nullptr, coefs, 1, nNodes);
    spmm_fused<0, 1><<<nodeBlocks, 256, 0, stream>>>(rowptr, pairsR, colptr, pairsC,
                                                     (const __half*)XAout, (const __half*)XAin,
                                                     nullptr, nullptr, sumH, out,
                                                     H, Theta, coefs, 2, nNodes);
}